// Round 11
// baseline (179.289 us; speedup 1.0000x reference)
//
#include <hip/hip_runtime.h>

#define K_SEL 103
typedef unsigned long long ull_t;
typedef _Float16 f16x8 __attribute__((ext_vector_type(8)));
typedef float f32x4 __attribute__((ext_vector_type(4)));

// ================= K12: fused (k2 select+MLP x2 | k1 lin+W2th) ==============
// grid 1280:
//  blocks [0,1024): q = bid>>1, par = bid&1. Both par-blocks run the full
//    selection (deterministic ascending-v compaction -> identical sel order);
//    par=0 runs MLP for k in [0,56) and stores Hh cols [0,56); par=1 for
//    k in [56,103) and cols [56,128) (incl zero pad). invtot written by both
//    (identical bits). Hh rows >=33 zero; unnormalized w (invtot in k3).
//  blocks [1024,1280): xlh = fp16(x @ W_lin^T + b) (64 rows each) + W2th.
__global__ __launch_bounds__(256, 5) void k12(const float* __restrict__ pos,
                                              const float* __restrict__ qpos,
                                              const float* __restrict__ Bmat,
                                              const float* __restrict__ W1,
                                              const float* __restrict__ b1,
                                              _Float16* __restrict__ Hh,
                                              int* __restrict__ indg,
                                              float* __restrict__ invtot,
                                              const float* __restrict__ x,
                                              const float* __restrict__ W,
                                              const float* __restrict__ b,
                                              _Float16* __restrict__ xlh,
                                              const float* __restrict__ W2,
                                              const float* __restrict__ filt,
                                              _Float16* __restrict__ W2th) {
    __shared__ __align__(16) unsigned char smem[30848];
    const int tid = threadIdx.x;
    const int bid = blockIdx.x;
    const int lane = tid & 63;
    const int wid = tid >> 6;

    if (bid >= 1024) {
        // ---------------- k1 path: 64 rows + W2th chunk --------------------
        const int bb = bid - 1024;
        float* Wt = (float*)smem;                  // 64x65 floats (pad: no 64-way conflict)
        for (int t2 = tid; t2 < 264; t2 += 256) {
            int t = bb * 264 + t2;                 // 256*264 = 67584 exactly
            int d = t & 31;
            int e = t >> 5;
            int c = e & 63;
            int j = e >> 6;
            float v = (j < 32) ? W2[(c * 32 + d) * 32 + j] : filt[c * 32 + d];
            W2th[d * 2112 + e] = (_Float16)v;
        }
        for (int t = tid; t < 4096; t += 256)
            Wt[(t & 63) * 65 + (t >> 6)] = W[t];
        __syncthreads();
        const int i = tid & 63;
        const int sub = tid >> 6;
        const float bi = b[i];
        #pragma unroll
        for (int rr = 0; rr < 4; ++rr) {
            const int r0 = bb * 64 + rr * 16 + sub * 4;
            float acc0 = bi, acc1 = bi, acc2 = bi, acc3 = bi;
            const float* xr = x + (size_t)r0 * 64;
            #pragma unroll 4
            for (int jj = 0; jj < 16; ++jj) {
                float4 v0 = *(const float4*)(xr + 0 * 64 + jj * 4);
                float4 v1 = *(const float4*)(xr + 1 * 64 + jj * 4);
                float4 v2 = *(const float4*)(xr + 2 * 64 + jj * 4);
                float4 v3 = *(const float4*)(xr + 3 * 64 + jj * 4);
                float w0 = Wt[(jj * 4 + 0) * 65 + i];
                float w1 = Wt[(jj * 4 + 1) * 65 + i];
                float w2 = Wt[(jj * 4 + 2) * 65 + i];
                float w3 = Wt[(jj * 4 + 3) * 65 + i];
                acc0 += v0.x * w0 + v0.y * w1 + v0.z * w2 + v0.w * w3;
                acc1 += v1.x * w0 + v1.y * w1 + v1.z * w2 + v1.w * w3;
                acc2 += v2.x * w0 + v2.y * w1 + v2.z * w2 + v2.w * w3;
                acc3 += v3.x * w0 + v3.y * w1 + v3.z * w2 + v3.w * w3;
            }
            xlh[(size_t)(r0 + 0) * 64 + i] = (_Float16)acc0;
            xlh[(size_t)(r0 + 1) * 64 + i] = (_Float16)acc1;
            xlh[(size_t)(r0 + 2) * 64 + i] = (_Float16)acc2;
            xlh[(size_t)(r0 + 3) * 64 + i] = (_Float16)acc3;
        }
        return;
    }

    // ---------------- k2 path: select + half-MLP ---------------------------
    const int q = bid >> 1;
    const int par = bid & 1;
    unsigned* ebits   = (unsigned*)(smem);            // 8192 B
    unsigned* hist    = (unsigned*)(smem + 8192);     // 16384 B
    _Float16* Hs      = (_Float16*)(smem + 8192);     // 12288 B (alias hist)
    float*    W1s     = (float*)(smem + 24576);       // 4096 B
    float*    b1s     = (float*)(smem + 28672);
    float*    Bm      = (float*)(smem + 28800);
    int*      sel_v   = (int*)(smem + 28928);         // 104
    float*    sel_e   = (float*)(smem + 29344);       // 104
    ull_t*    bnd     = (ull_t*)(smem + 29760);       // 128
    int*      counters= (int*)(smem + 30784);
    int*      info    = (int*)(smem + 30792);
    float*    wred    = (float*)(smem + 30800);       // 4
    float*    emax_s  = (float*)(smem + 30816);
    unsigned* wscan   = (unsigned*)(smem + 30824);    // 4

    for (int t = tid; t < 1024; t += 256) W1s[t] = W1[t];
    if (tid < 32) { b1s[tid] = b1[tid]; Bm[tid] = Bmat[tid]; }
    if (tid < 2)  counters[tid] = 0;
    for (int t = tid; t < 1024; t += 256) ((uint4*)hist)[t] = make_uint4(0, 0, 0, 0);
    const float qp0 = qpos[q * 2 + 0];
    const float qp1 = qpos[q * 2 + 1];
    __syncthreads();

    float lmin = 1e30f;
    for (int v = tid; v < 2048; v += 256) {
        float2 p = ((const float2*)pos)[v];
        float d0 = qp0 - p.x;
        float d1 = qp1 - p.y;
        d0 += 0.5f; d0 -= floorf(d0); d0 -= 0.5f;
        d1 += 0.5f; d1 -= floorf(d1); d1 -= 0.5f;
        float e = d0 * d0 + d1 * d1;
        ebits[v] = __float_as_uint(e);
        lmin = fminf(lmin, e);
        int bb2 = (int)(e * 8192.0f); bb2 = (bb2 > 4095) ? 4095 : bb2;
        atomicAdd(&hist[bb2], 1u);
    }
    #pragma unroll
    for (int off = 32; off > 0; off >>= 1)
        lmin = fminf(lmin, __shfl_xor(lmin, off, 64));
    if (lane == 0) wred[wid] = lmin;
    __syncthreads();
    const float e_min = fminf(fminf(wred[0], wred[1]), fminf(wred[2], wred[3]));

    // ---- hist scan -> boundary bin Bstar, count-below L
    unsigned lsum = 0;
    #pragma unroll
    for (int i = 0; i < 16; ++i) lsum += hist[tid * 16 + i];
    unsigned vq = lsum;
    #pragma unroll
    for (int off = 1; off < 64; off <<= 1) {
        unsigned n = __shfl_up(vq, off, 64);
        if (lane >= off) vq += n;
    }
    if (lane == 63) wscan[wid] = vq;
    __syncthreads();
    unsigned base = 0;
    for (int w2 = 0; w2 < wid; ++w2) base += wscan[w2];
    unsigned cum = base + vq - lsum;
    #pragma unroll
    for (int i = 0; i < 16; ++i) {
        unsigned cnt = hist[tid * 16 + i];
        if (cum <= 102u && 102u < cum + cnt) { info[0] = tid * 16 + i; info[1] = (int)cum; }
        cum += cnt;
    }
    __syncthreads();          // hist reads done -> hist dead (Hs aliases it)
    const int Bstar = info[0];
    const int L = info[1];
    const int need = K_SEL - L;

    // zero Hs (aliases dead hist)
    {
        f16x8 z = {0, 0, 0, 0, 0, 0, 0, 0};
        for (int t = tid; t < 768; t += 256) ((f16x8*)Hs)[t] = z;
    }

    // ---- DETERMINISTIC compaction (ascending v): both par-blocks agree.
    int myv[8]; float mye[8]; int mycnt = 0;
    #pragma unroll
    for (int i2 = 0; i2 < 8; ++i2) {
        int v = tid * 8 + i2;
        unsigned bb2 = ebits[v];
        float e = __uint_as_float(bb2);
        int bin = (int)(e * 8192.0f); bin = (bin > 4095) ? 4095 : bin;
        if (bin < Bstar) { myv[mycnt] = v; mye[mycnt] = e; ++mycnt; }
        else if (bin == Bstar) {
            int s2 = atomicAdd(&counters[1], 1);
            if (s2 < 128) bnd[s2] = (((ull_t)bb2) << 32) | (unsigned)v;
        }
    }
    unsigned vq2 = (unsigned)mycnt;
    #pragma unroll
    for (int off = 1; off < 64; off <<= 1) {
        unsigned n = __shfl_up(vq2, off, 64);
        if (lane >= off) vq2 += n;
    }
    if (lane == 63) wscan[wid] = vq2;
    __syncthreads();
    unsigned base2 = 0;
    for (int w2 = 0; w2 < wid; ++w2) base2 += wscan[w2];
    int P = (int)(base2 + vq2) - mycnt;
    for (int j2 = 0; j2 < mycnt; ++j2) { sel_v[P + j2] = myv[j2]; sel_e[P + j2] = mye[j2]; }
    __syncthreads();
    if (tid == 0) {
        int nb = counters[1]; if (nb > 128) nb = 128;
        for (int i = 1; i < nb; ++i) {      // full sort by (ebits,idx): deterministic
            ull_t key = bnd[i]; int j2 = i - 1;
            while (j2 >= 0 && bnd[j2] > key) { bnd[j2 + 1] = bnd[j2]; --j2; }
            bnd[j2 + 1] = key;
        }
        for (int i = 0; i < need; ++i) {
            sel_v[L + i] = (int)(unsigned)(bnd[i] & 0xffffffffull);
            sel_e[L + i] = __uint_as_float((unsigned)(bnd[i] >> 32));
        }
        emax_s[0] = __uint_as_float((unsigned)(bnd[need - 1] >> 32));
    }
    __syncthreads();

    const float denom = (emax_s[0] - e_min) + 1e-8f;
    float w = 0.0f;
    if (tid < K_SEL) {
        w = __expf(-(sel_e[tid] - e_min) / denom);
        sel_e[tid] = w;
    }
    float sw = w;
    #pragma unroll
    for (int off = 32; off > 0; off >>= 1)
        sw += __shfl_xor(sw, off, 64);
    if (lane == 0) wred[wid] = sw;
    __syncthreads();
    if (tid == 0)
        invtot[q] = 1.0f / (wred[0] + wred[1] + wred[2] + wred[3]);

    // ---- half-MLP: par 0 -> k in [0,56), par 1 -> k in [56,103)
    const int kbase = par * 56;
    const int kcnt  = par ? (K_SEL - 56) : 56;
    if (tid < 2 * kcnt) {
        const int k = kbase + (tid >> 1);
        const int io = (tid & 1) * 16;
        const int v = sel_v[k];
        const float wk = sel_e[k];
        float2 p = ((const float2*)pos)[v];
        float d0 = qp0 - p.x;
        float d1 = qp1 - p.y;
        d0 += 0.5f; d0 -= floorf(d0); d0 -= 0.5f;
        d1 += 0.5f; d1 -= floorf(d1); d1 -= 0.5f;
        float kf[32];
        #pragma unroll
        for (int f = 0; f < 16; ++f) {
            float t = d0 * Bm[f] + d1 * Bm[16 + f];   // revolutions
            float r = t - rintf(t);
            kf[f]      = __builtin_amdgcn_sinf(r);
            kf[16 + f] = __builtin_amdgcn_cosf(r);
        }
        #pragma unroll 4
        for (int i = io; i < io + 16; ++i) {
            float pre = b1s[i];
            #pragma unroll
            for (int jf = 0; jf < 32; ++jf) pre += kf[jf] * W1s[i * 32 + jf];
            float g = 0.5f * pre * (1.0f + erff(pre * 0.70710678118654752f));
            Hs[i * 128 + k] = (_Float16)(g * wk);
        }
        if (io == 0) {
            Hs[32 * 128 + k] = (_Float16)wk;
            indg[q * K_SEL + k] = v;
        }
    }
    __syncthreads();
    // ---- Hh slice store (coalesced f16x8)
    {
        _Float16* hq = Hh + (size_t)q * 6144;
        if (par == 0) {
            for (int t = tid; t < 336; t += 256) {    // 48 rows x 7 chunks: cols [0,56)
                int row = t / 7, c8 = t - row * 7;
                int off = row * 128 + c8 * 8;
                *(f16x8*)(hq + off) = *(const f16x8*)(&Hs[off]);
            }
        } else {
            for (int t = tid; t < 432; t += 256) {    // 48 rows x 9 chunks: cols [56,128)
                int row = t / 9, c8 = t - row * 9;
                int off = row * 128 + 56 + c8 * 8;
                *(f16x8*)(hq + off) = *(const f16x8*)(&Hs[off]);
            }
        }
    }
}

// ---------------- K3: MFMA GEMM1+GEMM2, block = (q, bt-half), 2 passes ------
// (R9 structure: grid 1024 = exactly 4 blocks/CU x 256 CUs, 1 residency round)
// Setup loaded once; pass-B gathers issued before pass-A GEMM1; first GEMM2
// W2th fragments prefetched before the gather barrier.
__global__ __launch_bounds__(256, 4) void k3_main(const _Float16* __restrict__ xlh,
                                                  const _Float16* __restrict__ Hh,
                                                  const int* __restrict__ indg,
                                                  const _Float16* __restrict__ W2th,
                                                  const float* __restrict__ bias,
                                                  const float* __restrict__ invtot,
                                                  float* __restrict__ out) {
    const int bid = blockIdx.x;
    const int q = bid >> 1;
    const int tid = threadIdx.x;
    const int lane = tid & 63;
    const int wv = tid >> 6;
    const int n0 = lane & 15;
    const int quad = lane >> 4;

    __shared__ __align__(16) unsigned char smem[36608];
    _Float16* Xg = (_Float16*)smem;                 // 17536 halfs (swizzled)
    _Float16* Zh = Xg;                              // alias (barrier-guarded)
    float* red = (float*)(smem + 35072);            // 1024 B
    int* ind_s = (int*)(smem + 36096);              // 128 ints

    // ---- setup (once for both passes)
    const _Float16* hq = Hh + (size_t)q * 6144;
    f16x8 afr[4][3];
    #pragma unroll
    for (int ks = 0; ks < 4; ++ks)
        #pragma unroll
        for (int r = 0; r < 3; ++r)
            afr[ks][r] = *(const f16x8*)(hq + (r * 16 + n0) * 128 + ks * 32 + quad * 8);
    const float it = invtot[q];
    const int e0f = wv * 32 + quad * 8;             // first GEMM2 step for this wave
    f16x8 pf0 = *(const f16x8*)(W2th + (size_t)(0 * 16 + n0) * 2112 + e0f);
    f16x8 pf1 = *(const f16x8*)(W2th + (size_t)(1 * 16 + n0) * 2112 + e0f);
    if (tid < 128) {
        int kk = (tid < K_SEL) ? tid : tid - K_SEL;
        ind_s[tid] = indg[q * K_SEL + kk];
    }
    __syncthreads();

    // gather slot decomposition: t = tid + i*256
    int g_bt[8], g_k[8], g_oct[8];
    #pragma unroll
    for (int i = 0; i < 8; ++i) {
        int t = tid + i * 256;
        g_bt[i] = t >> 10;
        int r = t & 1023;
        g_k[i] = r >> 3;
        g_oct[i] = r & 7;
    }
    const int bt0A = (bid & 1) * 4;
    const int bt0B = bt0A + 2;

    // ---- pass A gather loads + LDS write
    {
        f16x8 v[8];
        #pragma unroll
        for (int i = 0; i < 8; ++i)
            v[i] = *(const f16x8*)(xlh + ((size_t)(bt0A + g_bt[i]) * 2048 + ind_s[g_k[i]]) * 64 + g_oct[i] * 8);
        #pragma unroll
        for (int i = 0; i < 8; ++i) {
            int base = g_bt[i] * 8768 + g_oct[i] * 1096 + g_k[i];
            #pragma unroll
            for (int jj = 0; jj < 8; ++jj) Xg[base + 136 * jj] = v[i][jj];
        }
    }
    __syncthreads();

    // ---- issue pass-B gather loads (in flight during pass-A compute)
    f16x8 vB[8];
    #pragma unroll
    for (int i = 0; i < 8; ++i)
        vB[i] = *(const f16x8*)(xlh + ((size_t)(bt0B + g_bt[i]) * 2048 + ind_s[g_k[i]]) * 64 + g_oct[i] * 8);

    #pragma unroll
    for (int pass = 0; pass < 2; ++pass) {
        const int bt0 = pass ? bt0B : bt0A;
        if (pass) {
            #pragma unroll
            for (int i = 0; i < 8; ++i) {
                int base = g_bt[i] * 8768 + g_oct[i] * 1096 + g_k[i];
                #pragma unroll
                for (int jj = 0; jj < 8; ++jj) Xg[base + 136 * jj] = vB[i][jj];
            }
            __syncthreads();
        }

        // ---- GEMM1
        f32x4 Dz[3][2];
        #pragma unroll
        for (int r = 0; r < 3; ++r)
            #pragma unroll
            for (int c = 0; c < 2; ++c) Dz[r][c] = (f32x4){0.f, 0.f, 0.f, 0.f};
        #pragma unroll
        for (int ks = 0; ks < 4; ++ks) {
            const int kbase = ks * 32 + quad * 8;
            #pragma unroll
            for (int ctl = 0; ctl < 2; ++ctl) {
                const int ct = wv * 2 + ctl;
                const int bt = ct >> 2;
                const int c = (ct & 3) * 16 + n0;
                f16x8 bfr = *(const f16x8*)(&Xg[bt * 8768 + c * 136 + ((c >> 3) << 3) + kbase]);
                #pragma unroll
                for (int r = 0; r < 3; ++r)
                    Dz[r][ctl] = __builtin_amdgcn_mfma_f32_16x16x32_f16(afr[ks][r], bfr, Dz[r][ctl], 0, 0, 0);
            }
        }
        __syncthreads();    // Xg reads done -> safe to write aliased Zh

        #pragma unroll
        for (int ctl = 0; ctl < 2; ++ctl) {
            const int ct = wv * 2 + ctl;
            const int bt = ct >> 2;
            const int c = (ct & 3) * 16 + n0;
            #pragma unroll
            for (int r = 0; r < 3; ++r)
                #pragma unroll
                for (int reg = 0; reg < 4; ++reg) {
                    int j = r * 16 + quad * 4 + reg;
                    if (j < 33) Zh[bt * 2112 + j * 64 + c] = (_Float16)Dz[r][ctl][reg];
                }
        }
        __syncthreads();

        // ---- GEMM2: dual accumulator chains; first step uses prefetched W2th
        f32x4 D2[2][2];
        #pragma unroll
        for (int p = 0; p < 2; ++p)
            #pragma unroll
            for (int dt = 0; dt < 2; ++dt) D2[p][dt] = (f32x4){0.f, 0.f, 0.f, 0.f};
        {
            f16x8 afr2 = {0, 0, 0, 0, 0, 0, 0, 0};
            if (n0 < 2) afr2 = *(const f16x8*)(&Zh[n0 * 2112 + e0f]);
            D2[0][0] = __builtin_amdgcn_mfma_f32_16x16x32_f16(afr2, pf0, D2[0][0], 0, 0, 0);
            D2[0][1] = __builtin_amdgcn_mfma_f32_16x16x32_f16(afr2, pf1, D2[0][1], 0, 0, 0);
        }
        int p = 1;
        #pragma unroll 2
        for (int s = wv + 4; s < 66; s += 4) {
            const int e0 = s * 32 + quad * 8;
            f16x8 afr2 = {0, 0, 0, 0, 0, 0, 0, 0};
            if (n0 < 2) afr2 = *(const f16x8*)(&Zh[n0 * 2112 + e0]);
            #pragma unroll
            for (int dt = 0; dt < 2; ++dt) {
                f16x8 bfr = *(const f16x8*)(W2th + (size_t)(dt * 16 + n0) * 2112 + e0);
                D2[p][dt] = __builtin_amdgcn_mfma_f32_16x16x32_f16(afr2, bfr, D2[p][dt], 0, 0, 0);
            }
            p ^= 1;
        }
        #pragma unroll
        for (int dt = 0; dt < 2; ++dt)
            D2[0][dt] = D2[0][dt] + D2[1][dt];

        if (quad == 0) {
            red[(wv * 4 + 0) * 16 + n0] = D2[0][0][0];   // dt0 bt0
            red[(wv * 4 + 1) * 16 + n0] = D2[0][0][1];   // dt0 bt1
            red[(wv * 4 + 2) * 16 + n0] = D2[0][1][0];   // dt1 bt0
            red[(wv * 4 + 3) * 16 + n0] = D2[0][1][1];   // dt1 bt1
        }
        __syncthreads();   // red ready AND all Zh reads done
        if (tid < 64) {
            const int bt = tid >> 5;
            const int d = tid & 31;
            const int dt = d >> 4;
            const int dn = d & 15;
            float s = 0.0f;
            #pragma unroll
            for (int w2 = 0; w2 < 4; ++w2)
                s += red[(w2 * 4 + dt * 2 + bt) * 16 + dn];
            out[((size_t)(bt0 + bt) * 512 + q) * 32 + d] = bias[d] + it * s;
        }
    }
}

// ---------------------------------------------------------------------------
extern "C" void kernel_launch(void* const* d_in, const int* in_sizes, int n_in,
                              void* d_out, int out_size, void* d_ws, size_t ws_size,
                              hipStream_t stream) {
    const float* x     = (const float*)d_in[0];   // (2,4,2048,64)
    const float* pos   = (const float*)d_in[1];   // (2048,2)
    const float* qpos  = (const float*)d_in[2];   // (512,2)
    const float* W_lin = (const float*)d_in[3];   // (64,64)
    const float* b_lin = (const float*)d_in[4];   // (64)
    const float* Bmat  = (const float*)d_in[5];   // (2,16)
    const float* W1    = (const float*)d_in[6];   // (32,32)
    const float* b1    = (const float*)d_in[7];   // (32)
    const float* W2    = (const float*)d_in[8];   // (2048,32)
    const float* filt  = (const float*)d_in[9];   // (2048)
    const float* bias  = (const float*)d_in[10];  // (32)
    float* out = (float*)d_out;

    float* ws = (float*)d_ws;
    _Float16* xlh    = (_Float16*)ws;               // 1048576 halfs
    _Float16* Hh     = (_Float16*)(ws + 524288);    // 512*6144 halfs
    int*      indg   = (int*)(ws + 2097152);        // 52736 ints
    _Float16* W2th   = (_Float16*)(ws + 2150144);   // 32*2112 halfs
    float*    invtot = ws + 2183936;                // 512 floats

    k12<<<1280, 256, 0, stream>>>(pos, qpos, Bmat, W1, b1, Hh, indg, invtot,
                                  x, W_lin, b_lin, xlh, W2, filt, W2th);
    k3_main<<<1024, 256, 0, stream>>>(xlh, Hh, indg, W2th, bias, invtot, out);
}

// Round 12
// 121.190 us; speedup vs baseline: 1.4794x; 1.4794x over previous
//
#include <hip/hip_runtime.h>

#define K_SEL 103
typedef unsigned long long ull_t;
typedef _Float16 f16x8 __attribute__((ext_vector_type(8)));
typedef float f32x4 __attribute__((ext_vector_type(4)));

// ================= K12: fused (k2 select+MLP | k1 lin+W2th) =================
// grid 1024 (= exactly 4 blocks/CU x 256 CUs, one residency round):
// blocks [0,512) = per-query selection + MLP -> Hh (A-layout, unnormalized;
//   invtot applied in k3), indg, invtot.
// blocks [512,1024) = xlh = fp16(x @ W_lin^T + b) (32 rows each) + W2th chunk.
__global__ __launch_bounds__(256, 4) void k12(const float* __restrict__ pos,
                                              const float* __restrict__ qpos,
                                              const float* __restrict__ Bmat,
                                              const float* __restrict__ W1,
                                              const float* __restrict__ b1,
                                              _Float16* __restrict__ Hh,
                                              int* __restrict__ indg,
                                              float* __restrict__ invtot,
                                              const float* __restrict__ x,
                                              const float* __restrict__ W,
                                              const float* __restrict__ b,
                                              _Float16* __restrict__ xlh,
                                              const float* __restrict__ W2,
                                              const float* __restrict__ filt,
                                              _Float16* __restrict__ W2th) {
    __shared__ __align__(16) unsigned char smem[30848];
    const int tid = threadIdx.x;
    const int bid = blockIdx.x;
    const int lane = tid & 63;
    const int wid = tid >> 6;

    if (bid >= 512) {
        // ---------------- k1 path: 32 rows + W2th chunk --------------------
        const int bb = bid - 512;
        float* Wt = (float*)smem;                  // 64x65 (pad: kills 64-way conflict)
        if (tid < 132) {
            int t = bb * 132 + tid;                // 512*132 = 67584 exactly
            int d = t & 31;
            int e = t >> 5;
            int c = e & 63;
            int j = e >> 6;
            float v = (j < 32) ? W2[(c * 32 + d) * 32 + j] : filt[c * 32 + d];
            W2th[d * 2112 + e] = (_Float16)v;
        }
        for (int t = tid; t < 4096; t += 256)
            Wt[(t & 63) * 65 + (t >> 6)] = W[t];
        __syncthreads();
        const int i = tid & 63;
        const int sub = tid >> 6;
        const float bi = b[i];
        #pragma unroll
        for (int rr = 0; rr < 2; ++rr) {
            const int r0 = bb * 32 + rr * 16 + sub * 4;
            float acc0 = bi, acc1 = bi, acc2 = bi, acc3 = bi;
            const float* xr = x + (size_t)r0 * 64;
            #pragma unroll 4
            for (int jj = 0; jj < 16; ++jj) {
                float4 v0 = *(const float4*)(xr + 0 * 64 + jj * 4);
                float4 v1 = *(const float4*)(xr + 1 * 64 + jj * 4);
                float4 v2 = *(const float4*)(xr + 2 * 64 + jj * 4);
                float4 v3 = *(const float4*)(xr + 3 * 64 + jj * 4);
                float w0 = Wt[(jj * 4 + 0) * 65 + i];
                float w1 = Wt[(jj * 4 + 1) * 65 + i];
                float w2 = Wt[(jj * 4 + 2) * 65 + i];
                float w3 = Wt[(jj * 4 + 3) * 65 + i];
                acc0 += v0.x * w0 + v0.y * w1 + v0.z * w2 + v0.w * w3;
                acc1 += v1.x * w0 + v1.y * w1 + v1.z * w2 + v1.w * w3;
                acc2 += v2.x * w0 + v2.y * w1 + v2.z * w2 + v2.w * w3;
                acc3 += v3.x * w0 + v3.y * w1 + v3.z * w2 + v3.w * w3;
            }
            xlh[(size_t)(r0 + 0) * 64 + i] = (_Float16)acc0;
            xlh[(size_t)(r0 + 1) * 64 + i] = (_Float16)acc1;
            xlh[(size_t)(r0 + 2) * 64 + i] = (_Float16)acc2;
            xlh[(size_t)(r0 + 3) * 64 + i] = (_Float16)acc3;
        }
        return;
    }

    // ---------------- k2 path: select + MLP (R9-proven) --------------------
    const int q = bid;
    unsigned* ebits   = (unsigned*)(smem);            // 8192 B
    unsigned* hist    = (unsigned*)(smem + 8192);     // 16384 B
    _Float16* Hs      = (_Float16*)(smem + 8192);     // 12288 B (alias hist)
    float*    W1s     = (float*)(smem + 24576);       // 4096 B
    float*    b1s     = (float*)(smem + 28672);
    float*    Bm      = (float*)(smem + 28800);
    int*      sel_v   = (int*)(smem + 28928);         // 104
    float*    sel_e   = (float*)(smem + 29344);       // 104
    ull_t*    bnd     = (ull_t*)(smem + 29760);       // 128
    int*      counters= (int*)(smem + 30784);
    int*      info    = (int*)(smem + 30792);
    float*    wred    = (float*)(smem + 30800);       // 4
    float*    emax_s  = (float*)(smem + 30816);
    unsigned* wscan   = (unsigned*)(smem + 30824);    // 4

    for (int t = tid; t < 1024; t += 256) W1s[t] = W1[t];
    if (tid < 32) { b1s[tid] = b1[tid]; Bm[tid] = Bmat[tid]; }
    if (tid < 2)  counters[tid] = 0;
    for (int t = tid; t < 1024; t += 256) ((uint4*)hist)[t] = make_uint4(0, 0, 0, 0);
    const float qp0 = qpos[q * 2 + 0];
    const float qp1 = qpos[q * 2 + 1];
    __syncthreads();

    float lmin = 1e30f;
    for (int v = tid; v < 2048; v += 256) {
        float2 p = ((const float2*)pos)[v];
        float d0 = qp0 - p.x;
        float d1 = qp1 - p.y;
        d0 += 0.5f; d0 -= floorf(d0); d0 -= 0.5f;
        d1 += 0.5f; d1 -= floorf(d1); d1 -= 0.5f;
        float e = d0 * d0 + d1 * d1;
        ebits[v] = __float_as_uint(e);
        lmin = fminf(lmin, e);
        int bb2 = (int)(e * 8192.0f); bb2 = (bb2 > 4095) ? 4095 : bb2;
        atomicAdd(&hist[bb2], 1u);
    }
    #pragma unroll
    for (int off = 32; off > 0; off >>= 1)
        lmin = fminf(lmin, __shfl_xor(lmin, off, 64));
    if (lane == 0) wred[wid] = lmin;
    __syncthreads();
    const float e_min = fminf(fminf(wred[0], wred[1]), fminf(wred[2], wred[3]));

    unsigned lsum = 0;
    #pragma unroll
    for (int i = 0; i < 16; ++i) lsum += hist[tid * 16 + i];
    unsigned vq = lsum;
    #pragma unroll
    for (int off = 1; off < 64; off <<= 1) {
        unsigned n = __shfl_up(vq, off, 64);
        if (lane >= off) vq += n;
    }
    if (lane == 63) wscan[wid] = vq;
    __syncthreads();
    unsigned base = 0;
    for (int w2 = 0; w2 < wid; ++w2) base += wscan[w2];
    unsigned cum = base + vq - lsum;
    #pragma unroll
    for (int i = 0; i < 16; ++i) {
        unsigned cnt = hist[tid * 16 + i];
        if (cum <= 102u && 102u < cum + cnt) { info[0] = tid * 16 + i; info[1] = (int)cum; }
        cum += cnt;
    }
    __syncthreads();          // all hist reads done -> hist dead
    const int Bstar = info[0];
    const int L = info[1];
    const int need = K_SEL - L;

    {   // zero Hs (aliases dead hist)
        f16x8 z = {0, 0, 0, 0, 0, 0, 0, 0};
        for (int t = tid; t < 768; t += 256) ((f16x8*)Hs)[t] = z;
    }
    for (int v = tid; v < 2048; v += 256) {
        unsigned bb2 = ebits[v];
        float e = __uint_as_float(bb2);
        int bin = (int)(e * 8192.0f); bin = (bin > 4095) ? 4095 : bin;
        if (bin < Bstar) {
            int s2 = atomicAdd(&counters[0], 1);
            sel_v[s2] = v; sel_e[s2] = e;
        } else if (bin == Bstar) {
            int s2 = atomicAdd(&counters[1], 1);
            if (s2 < 128) bnd[s2] = (((ull_t)bb2) << 32) | (unsigned)v;
        }
    }
    __syncthreads();
    if (tid == 0) {
        int nb = counters[1]; if (nb > 128) nb = 128;
        for (int i = 1; i < nb; ++i) {
            ull_t key = bnd[i]; int j2 = i - 1;
            while (j2 >= 0 && bnd[j2] > key) { bnd[j2 + 1] = bnd[j2]; --j2; }
            bnd[j2 + 1] = key;
        }
        for (int i = 0; i < need; ++i) {
            sel_v[L + i] = (int)(unsigned)(bnd[i] & 0xffffffffull);
            sel_e[L + i] = __uint_as_float((unsigned)(bnd[i] >> 32));
        }
        emax_s[0] = __uint_as_float((unsigned)(bnd[need - 1] >> 32));
    }
    __syncthreads();

    const float denom = (emax_s[0] - e_min) + 1e-8f;
    float w = 0.0f;
    if (tid < K_SEL) {
        w = __expf(-(sel_e[tid] - e_min) / denom);
        sel_e[tid] = w;
    }
    float sw = w;
    #pragma unroll
    for (int off = 32; off > 0; off >>= 1)
        sw += __shfl_xor(sw, off, 64);
    if (lane == 0) wred[wid] = sw;
    __syncthreads();
    if (tid == 0)
        invtot[q] = 1.0f / (wred[0] + wred[1] + wred[2] + wred[3]);

    if (tid < 2 * K_SEL) {
        const int k = tid >> 1;
        const int io = (tid & 1) * 16;
        const int v = sel_v[k];
        const float wk = sel_e[k];
        float2 p = ((const float2*)pos)[v];
        float d0 = qp0 - p.x;
        float d1 = qp1 - p.y;
        d0 += 0.5f; d0 -= floorf(d0); d0 -= 0.5f;
        d1 += 0.5f; d1 -= floorf(d1); d1 -= 0.5f;
        float kf[32];
        #pragma unroll
        for (int f = 0; f < 16; ++f) {
            float t = d0 * Bm[f] + d1 * Bm[16 + f];   // revolutions
            float r = t - rintf(t);
            kf[f]      = __builtin_amdgcn_sinf(r);
            kf[16 + f] = __builtin_amdgcn_cosf(r);
        }
        #pragma unroll 4
        for (int i = io; i < io + 16; ++i) {
            float pre = b1s[i];
            #pragma unroll
            for (int jf = 0; jf < 32; ++jf) pre += kf[jf] * W1s[i * 32 + jf];
            float g = 0.5f * pre * (1.0f + erff(pre * 0.70710678118654752f));
            Hs[i * 128 + k] = (_Float16)(g * wk);
        }
        if (io == 0) {
            Hs[32 * 128 + k] = (_Float16)wk;
            indg[q * K_SEL + k] = v;
        }
    }
    __syncthreads();
    {
        _Float16* hq = Hh + (size_t)q * 6144;
        for (int t = tid; t < 768; t += 256)
            ((f16x8*)hq)[t] = ((const f16x8*)Hs)[t];
    }
}

// ---------------- K3: 4 x 1-bt GEMM1 passes + ONE M=4 GEMM2 -----------------
// grid 1024 = (q, bt-half). W2th streamed ONCE per block (halves the dominant
// L2 traffic vs R9's per-pass GEMM2). Xg single-bt swizzled (c*136+8*(c>>3)+k);
// Zh4[4][2112] separate region; red aliases dead Xg. Next pass's gathers
// issued during current GEMM1.
__global__ __launch_bounds__(256, 4) void k3_main(const _Float16* __restrict__ xlh,
                                                  const _Float16* __restrict__ Hh,
                                                  const int* __restrict__ indg,
                                                  const _Float16* __restrict__ W2th,
                                                  const float* __restrict__ bias,
                                                  const float* __restrict__ invtot,
                                                  float* __restrict__ out) {
    const int bid = blockIdx.x;
    const int q = bid >> 1;
    const int bt0 = (bid & 1) * 4;
    const int tid = threadIdx.x;
    const int lane = tid & 63;
    const int wv = tid >> 6;
    const int n0 = lane & 15;
    const int quad = lane >> 4;

    __shared__ __align__(16) unsigned char smem[34944];
    _Float16* Xg  = (_Float16*)smem;                 // 8768 halfs = 17536 B
    _Float16* Zh4 = (_Float16*)(smem + 17536);       // 4*2112 halfs = 16896 B
    int* ind_s    = (int*)(smem + 34432);            // 128 ints
    float* red    = (float*)smem;                    // aliases dead Xg (512 f)

    // ---- setup (once)
    const _Float16* hq = Hh + (size_t)q * 6144;
    f16x8 afr[4][3];
    #pragma unroll
    for (int ks = 0; ks < 4; ++ks)
        #pragma unroll
        for (int r = 0; r < 3; ++r)
            afr[ks][r] = *(const f16x8*)(hq + (r * 16 + n0) * 128 + ks * 32 + quad * 8);
    const float it = invtot[q];
    const int e0f = wv * 32 + quad * 8;
    f16x8 pf0 = *(const f16x8*)(W2th + (size_t)(0 * 16 + n0) * 2112 + e0f);
    f16x8 pf1 = *(const f16x8*)(W2th + (size_t)(1 * 16 + n0) * 2112 + e0f);
    if (tid < 128) {
        int kk = (tid < K_SEL) ? tid : tid - K_SEL;
        ind_s[tid] = indg[q * K_SEL + kk];
    }
    __syncthreads();

    // gather slot decomposition: slot = tid + i*256, i<4 (covers 1024 slots)
    int g_k[4], g_oct[4];
    #pragma unroll
    for (int i = 0; i < 4; ++i) {
        int t = tid + i * 256;
        g_k[i] = t >> 3;
        g_oct[i] = t & 7;
    }

    // ---- pass-0 gather
    {
        f16x8 v0[4];
        #pragma unroll
        for (int i = 0; i < 4; ++i)
            v0[i] = *(const f16x8*)(xlh + ((size_t)bt0 * 2048 + ind_s[g_k[i]]) * 64 + g_oct[i] * 8);
        #pragma unroll
        for (int i = 0; i < 4; ++i) {
            int base = g_oct[i] * 1096 + g_k[i];
            #pragma unroll
            for (int jj = 0; jj < 8; ++jj) Xg[base + 136 * jj] = v0[i][jj];
        }
    }
    __syncthreads();

    const int cA = wv * 16 + n0;
    const int cswz = cA * 136 + ((cA >> 3) << 3);

    #pragma unroll
    for (int p = 0; p < 4; ++p) {
        // prefetch next pass's gathers (in flight during GEMM1)
        f16x8 vn[4];
        if (p < 3) {
            #pragma unroll
            for (int i = 0; i < 4; ++i)
                vn[i] = *(const f16x8*)(xlh + ((size_t)(bt0 + p + 1) * 2048 + ind_s[g_k[i]]) * 64 + g_oct[i] * 8);
        }
        // GEMM1 (1 bt, N=64: wave wv owns c-tile wv)
        f32x4 Dz[3];
        #pragma unroll
        for (int r = 0; r < 3; ++r) Dz[r] = (f32x4){0.f, 0.f, 0.f, 0.f};
        #pragma unroll
        for (int ks = 0; ks < 4; ++ks) {
            f16x8 bfr = *(const f16x8*)(&Xg[cswz + ks * 32 + quad * 8]);
            #pragma unroll
            for (int r = 0; r < 3; ++r)
                Dz[r] = __builtin_amdgcn_mfma_f32_16x16x32_f16(afr[ks][r], bfr, Dz[r], 0, 0, 0);
        }
        __syncthreads();          // Xg reads done
        // Zh4[p] write (disjoint from Xg; no extra barrier needed)
        #pragma unroll
        for (int r = 0; r < 3; ++r)
            #pragma unroll
            for (int reg = 0; reg < 4; ++reg) {
                int j = r * 16 + quad * 4 + reg;
                if (j < 33) Zh4[p * 2112 + j * 64 + cA] = (_Float16)Dz[r][reg];
            }
        if (p < 3) {
            #pragma unroll
            for (int i = 0; i < 4; ++i) {
                int base = g_oct[i] * 1096 + g_k[i];
                #pragma unroll
                for (int jj = 0; jj < 8; ++jj) Xg[base + 136 * jj] = vn[i][jj];
            }
            __syncthreads();
        }
    }
    __syncthreads();              // all Zh4 writes visible

    // ---- GEMM2 (M=4): ONE W2th pass, dual accumulator chains
    f32x4 D2[2][2];
    #pragma unroll
    for (int pp = 0; pp < 2; ++pp)
        #pragma unroll
        for (int dt = 0; dt < 2; ++dt) D2[pp][dt] = (f32x4){0.f, 0.f, 0.f, 0.f};
    {
        f16x8 a2 = {0, 0, 0, 0, 0, 0, 0, 0};
        if (n0 < 4) a2 = *(const f16x8*)(&Zh4[n0 * 2112 + e0f]);
        D2[0][0] = __builtin_amdgcn_mfma_f32_16x16x32_f16(a2, pf0, D2[0][0], 0, 0, 0);
        D2[0][1] = __builtin_amdgcn_mfma_f32_16x16x32_f16(a2, pf1, D2[0][1], 0, 0, 0);
    }
    int pp = 1;
    #pragma unroll 2
    for (int s = wv + 4; s < 66; s += 4) {
        const int e0 = s * 32 + quad * 8;
        f16x8 a2 = {0, 0, 0, 0, 0, 0, 0, 0};
        if (n0 < 4) a2 = *(const f16x8*)(&Zh4[n0 * 2112 + e0]);
        #pragma unroll
        for (int dt = 0; dt < 2; ++dt) {
            f16x8 bfr = *(const f16x8*)(W2th + (size_t)(dt * 16 + n0) * 2112 + e0);
            D2[pp][dt] = __builtin_amdgcn_mfma_f32_16x16x32_f16(a2, bfr, D2[pp][dt], 0, 0, 0);
        }
        pp ^= 1;
    }
    #pragma unroll
    for (int dt = 0; dt < 2; ++dt)
        D2[0][dt] = D2[0][dt] + D2[1][dt];

    // red[wv][dt][bt][n0] (aliases Xg: last Xg read already barrier-fenced)
    if (quad == 0) {
        #pragma unroll
        for (int dt = 0; dt < 2; ++dt)
            #pragma unroll
            for (int reg = 0; reg < 4; ++reg)
                red[((wv * 2 + dt) * 4 + reg) * 16 + n0] = D2[0][dt][reg];
    }
    __syncthreads();
    if (tid < 128) {
        const int bt = tid >> 5;
        const int d = tid & 31;
        const int dt = d >> 4;
        const int dn = d & 15;
        float s = 0.0f;
        #pragma unroll
        for (int w2 = 0; w2 < 4; ++w2)
            s += red[((w2 * 2 + dt) * 4 + bt) * 16 + dn];
        out[((size_t)(bt0 + bt) * 512 + q) * 32 + d] = bias[d] + it * s;
    }
}

// ---------------------------------------------------------------------------
extern "C" void kernel_launch(void* const* d_in, const int* in_sizes, int n_in,
                              void* d_out, int out_size, void* d_ws, size_t ws_size,
                              hipStream_t stream) {
    const float* x     = (const float*)d_in[0];   // (2,4,2048,64)
    const float* pos   = (const float*)d_in[1];   // (2048,2)
    const float* qpos  = (const float*)d_in[2];   // (512,2)
    const float* W_lin = (const float*)d_in[3];   // (64,64)
    const float* b_lin = (const float*)d_in[4];   // (64)
    const float* Bmat  = (const float*)d_in[5];   // (2,16)
    const float* W1    = (const float*)d_in[6];   // (32,32)
    const float* b1    = (const float*)d_in[7];   // (32)
    const float* W2    = (const float*)d_in[8];   // (2048,32)
    const float* filt  = (const float*)d_in[9];   // (2048)
    const float* bias  = (const float*)d_in[10];  // (32)
    float* out = (float*)d_out;

    float* ws = (float*)d_ws;
    _Float16* xlh    = (_Float16*)ws;               // 1048576 halfs
    _Float16* Hh     = (_Float16*)(ws + 524288);    // 512*6144 halfs
    int*      indg   = (int*)(ws + 2097152);        // 52736 ints
    _Float16* W2th   = (_Float16*)(ws + 2150144);   // 32*2112 halfs
    float*    invtot = ws + 2183936;                // 512 floats

    k12<<<1024, 256, 0, stream>>>(pos, qpos, Bmat, W1, b1, Hh, indg, invtot,
                                  x, W_lin, b_lin, xlh, W2, filt, W2th);
    k3_main<<<1024, 256, 0, stream>>>(xlh, Hh, indg, W2th, bias, invtot, out);
}

// Round 13
// 119.692 us; speedup vs baseline: 1.4979x; 1.0125x over previous
//
#include <hip/hip_runtime.h>

#define K_SEL 103
typedef unsigned long long ull_t;
typedef _Float16 f16x8 __attribute__((ext_vector_type(8)));
typedef float f32x4 __attribute__((ext_vector_type(4)));

// ================= K12: fused (k2 select+MLP | k1 lin+W2th), B=512 ==========
// grid 768 = exactly 3 blocks/CU x 256 CUs (one residency round):
// blocks [0,512) = per-query selection + MLP -> Hh (A-layout, unnormalized;
//   invtot applied in k3), indg, invtot.    (8 waves: MLP tail 4 threads/k)
// blocks [512,768) = xlh = fp16(x @ W_lin^T + b) (64 rows each) + W2th chunk.
__global__ __launch_bounds__(512, 6) void k12(const float* __restrict__ pos,
                                              const float* __restrict__ qpos,
                                              const float* __restrict__ Bmat,
                                              const float* __restrict__ W1,
                                              const float* __restrict__ b1,
                                              _Float16* __restrict__ Hh,
                                              int* __restrict__ indg,
                                              float* __restrict__ invtot,
                                              const float* __restrict__ x,
                                              const float* __restrict__ W,
                                              const float* __restrict__ b,
                                              _Float16* __restrict__ xlh,
                                              const float* __restrict__ W2,
                                              const float* __restrict__ filt,
                                              _Float16* __restrict__ W2th) {
    __shared__ __align__(16) unsigned char smem[30880];
    const int tid = threadIdx.x;
    const int bid = blockIdx.x;
    const int lane = tid & 63;
    const int wid = tid >> 6;          // 0..7

    if (bid >= 512) {
        // ---------------- k1 path: 64 rows + W2th chunk --------------------
        const int bb = bid - 512;
        float* Wt = (float*)smem;                  // 64x65 (pad kills 64-way conflict)
        if (tid < 264) {
            int t = bb * 264 + tid;                // 256*264 = 67584 exactly
            int d = t & 31;
            int e = t >> 5;
            int c = e & 63;
            int j = e >> 6;
            float v = (j < 32) ? W2[(c * 32 + d) * 32 + j] : filt[c * 32 + d];
            W2th[d * 2112 + e] = (_Float16)v;
        }
        for (int t = tid; t < 4096; t += 512)
            Wt[(t & 63) * 65 + (t >> 6)] = W[t];
        __syncthreads();
        const int i = tid & 63;
        const int sub = tid >> 6;                  // 0..7
        const float bi = b[i];
        #pragma unroll
        for (int rr = 0; rr < 2; ++rr) {
            const int r0 = bb * 64 + rr * 32 + sub * 4;
            float acc0 = bi, acc1 = bi, acc2 = bi, acc3 = bi;
            const float* xr = x + (size_t)r0 * 64;
            #pragma unroll 4
            for (int jj = 0; jj < 16; ++jj) {
                float4 v0 = *(const float4*)(xr + 0 * 64 + jj * 4);
                float4 v1 = *(const float4*)(xr + 1 * 64 + jj * 4);
                float4 v2 = *(const float4*)(xr + 2 * 64 + jj * 4);
                float4 v3 = *(const float4*)(xr + 3 * 64 + jj * 4);
                float w0 = Wt[(jj * 4 + 0) * 65 + i];
                float w1 = Wt[(jj * 4 + 1) * 65 + i];
                float w2 = Wt[(jj * 4 + 2) * 65 + i];
                float w3 = Wt[(jj * 4 + 3) * 65 + i];
                acc0 += v0.x * w0 + v0.y * w1 + v0.z * w2 + v0.w * w3;
                acc1 += v1.x * w0 + v1.y * w1 + v1.z * w2 + v1.w * w3;
                acc2 += v2.x * w0 + v2.y * w1 + v2.z * w2 + v2.w * w3;
                acc3 += v3.x * w0 + v3.y * w1 + v3.z * w2 + v3.w * w3;
            }
            xlh[(size_t)(r0 + 0) * 64 + i] = (_Float16)acc0;
            xlh[(size_t)(r0 + 1) * 64 + i] = (_Float16)acc1;
            xlh[(size_t)(r0 + 2) * 64 + i] = (_Float16)acc2;
            xlh[(size_t)(r0 + 3) * 64 + i] = (_Float16)acc3;
        }
        return;
    }

    // ---------------- k2 path: select + MLP --------------------------------
    const int q = bid;
    unsigned* ebits   = (unsigned*)(smem);            // 8192 B
    unsigned* hist    = (unsigned*)(smem + 8192);     // 16384 B
    _Float16* Hs      = (_Float16*)(smem + 8192);     // 12288 B (alias hist)
    float*    W1s     = (float*)(smem + 24576);       // 4096 B
    float*    b1s     = (float*)(smem + 28672);
    float*    Bm      = (float*)(smem + 28800);
    int*      sel_v   = (int*)(smem + 28928);         // 104
    float*    sel_e   = (float*)(smem + 29344);       // 104
    ull_t*    bnd     = (ull_t*)(smem + 29760);       // 128
    int*      counters= (int*)(smem + 30784);         // 2
    int*      info    = (int*)(smem + 30792);         // 2
    float*    wred    = (float*)(smem + 30800);       // 8
    float*    emax_s  = (float*)(smem + 30832);       // 1
    unsigned* wscan   = (unsigned*)(smem + 30836);    // 8

    for (int t = tid; t < 1024; t += 512) W1s[t] = W1[t];
    if (tid < 32) { b1s[tid] = b1[tid]; Bm[tid] = Bmat[tid]; }
    if (tid < 2)  counters[tid] = 0;
    for (int t = tid; t < 1024; t += 512) ((uint4*)hist)[t] = make_uint4(0, 0, 0, 0);
    const float qp0 = qpos[q * 2 + 0];
    const float qp1 = qpos[q * 2 + 1];
    __syncthreads();

    float lmin = 1e30f;
    for (int v = tid; v < 2048; v += 512) {
        float2 p = ((const float2*)pos)[v];
        float d0 = qp0 - p.x;
        float d1 = qp1 - p.y;
        d0 += 0.5f; d0 -= floorf(d0); d0 -= 0.5f;
        d1 += 0.5f; d1 -= floorf(d1); d1 -= 0.5f;
        float e = d0 * d0 + d1 * d1;
        ebits[v] = __float_as_uint(e);
        lmin = fminf(lmin, e);
        int bb2 = (int)(e * 8192.0f); bb2 = (bb2 > 4095) ? 4095 : bb2;
        atomicAdd(&hist[bb2], 1u);
    }
    #pragma unroll
    for (int off = 32; off > 0; off >>= 1)
        lmin = fminf(lmin, __shfl_xor(lmin, off, 64));
    if (lane == 0) wred[wid] = lmin;
    __syncthreads();
    float e_min = wred[0];
    #pragma unroll
    for (int w2 = 1; w2 < 8; ++w2) e_min = fminf(e_min, wred[w2]);

    // ---- hist scan: 8 bins/thread
    unsigned lsum = 0;
    #pragma unroll
    for (int i = 0; i < 8; ++i) lsum += hist[tid * 8 + i];
    unsigned vq = lsum;
    #pragma unroll
    for (int off = 1; off < 64; off <<= 1) {
        unsigned n = __shfl_up(vq, off, 64);
        if (lane >= off) vq += n;
    }
    if (lane == 63) wscan[wid] = vq;
    __syncthreads();
    unsigned base = 0;
    for (int w2 = 0; w2 < wid; ++w2) base += wscan[w2];
    unsigned cum = base + vq - lsum;
    #pragma unroll
    for (int i = 0; i < 8; ++i) {
        unsigned cnt = hist[tid * 8 + i];
        if (cum <= 102u && 102u < cum + cnt) { info[0] = tid * 8 + i; info[1] = (int)cum; }
        cum += cnt;
    }
    __syncthreads();          // all hist reads done -> hist dead
    const int Bstar = info[0];
    const int L = info[1];
    const int need = K_SEL - L;

    {   // zero Hs (aliases dead hist)
        f16x8 z = {0, 0, 0, 0, 0, 0, 0, 0};
        for (int t = tid; t < 768; t += 512) ((f16x8*)Hs)[t] = z;
    }
    for (int v = tid; v < 2048; v += 512) {
        unsigned bb2 = ebits[v];
        float e = __uint_as_float(bb2);
        int bin = (int)(e * 8192.0f); bin = (bin > 4095) ? 4095 : bin;
        if (bin < Bstar) {
            int s2 = atomicAdd(&counters[0], 1);
            sel_v[s2] = v; sel_e[s2] = e;
        } else if (bin == Bstar) {
            int s2 = atomicAdd(&counters[1], 1);
            if (s2 < 128) bnd[s2] = (((ull_t)bb2) << 32) | (unsigned)v;
        }
    }
    __syncthreads();
    if (tid == 0) {
        int nb = counters[1]; if (nb > 128) nb = 128;
        for (int i = 1; i < nb; ++i) {
            ull_t key = bnd[i]; int j2 = i - 1;
            while (j2 >= 0 && bnd[j2] > key) { bnd[j2 + 1] = bnd[j2]; --j2; }
            bnd[j2 + 1] = key;
        }
        for (int i = 0; i < need; ++i) {
            sel_v[L + i] = (int)(unsigned)(bnd[i] & 0xffffffffull);
            sel_e[L + i] = __uint_as_float((unsigned)(bnd[i] >> 32));
        }
        emax_s[0] = __uint_as_float((unsigned)(bnd[need - 1] >> 32));
    }
    __syncthreads();

    const float denom = (emax_s[0] - e_min) + 1e-8f;
    float w = 0.0f;
    if (tid < K_SEL) {
        w = __expf(-(sel_e[tid] - e_min) / denom);
        sel_e[tid] = w;
    }
    float sw = w;
    #pragma unroll
    for (int off = 32; off > 0; off >>= 1)
        sw += __shfl_xor(sw, off, 64);
    if (lane == 0) wred[wid] = sw;
    __syncthreads();
    if (tid == 0) {
        float tot = 0.0f;
        #pragma unroll
        for (int w2 = 0; w2 < 8; ++w2) tot += wred[w2];
        invtot[q] = 1.0f / tot;
    }

    // ---- MLP with unnormalized w: 4 threads per k (8 outputs each)
    if (tid < 4 * K_SEL) {
        const int k = tid >> 2;
        const int io = (tid & 3) * 8;
        const int v = sel_v[k];
        const float wk = sel_e[k];
        float2 p = ((const float2*)pos)[v];
        float d0 = qp0 - p.x;
        float d1 = qp1 - p.y;
        d0 += 0.5f; d0 -= floorf(d0); d0 -= 0.5f;
        d1 += 0.5f; d1 -= floorf(d1); d1 -= 0.5f;
        float kf[32];
        #pragma unroll
        for (int f = 0; f < 16; ++f) {
            float t = d0 * Bm[f] + d1 * Bm[16 + f];   // revolutions
            float r = t - rintf(t);
            kf[f]      = __builtin_amdgcn_sinf(r);
            kf[16 + f] = __builtin_amdgcn_cosf(r);
        }
        #pragma unroll
        for (int i = io; i < io + 8; ++i) {
            float pre = b1s[i];
            #pragma unroll
            for (int jf = 0; jf < 32; ++jf) pre += kf[jf] * W1s[i * 32 + jf];
            float g = 0.5f * pre * (1.0f + erff(pre * 0.70710678118654752f));
            Hs[i * 128 + k] = (_Float16)(g * wk);
        }
        if (io == 0) {
            Hs[32 * 128 + k] = (_Float16)wk;
            indg[q * K_SEL + k] = v;
        }
    }
    __syncthreads();
    {
        _Float16* hq = Hh + (size_t)q * 6144;
        for (int t = tid; t < 768; t += 512)
            ((f16x8*)hq)[t] = ((const f16x8*)Hs)[t];
    }
}

// ---------------- K3: 4 x 1-bt GEMM1 passes + ONE M=4 GEMM2 (R12-proven) ----
__global__ __launch_bounds__(256, 4) void k3_main(const _Float16* __restrict__ xlh,
                                                  const _Float16* __restrict__ Hh,
                                                  const int* __restrict__ indg,
                                                  const _Float16* __restrict__ W2th,
                                                  const float* __restrict__ bias,
                                                  const float* __restrict__ invtot,
                                                  float* __restrict__ out) {
    const int bid = blockIdx.x;
    const int q = bid >> 1;
    const int bt0 = (bid & 1) * 4;
    const int tid = threadIdx.x;
    const int lane = tid & 63;
    const int wv = tid >> 6;
    const int n0 = lane & 15;
    const int quad = lane >> 4;

    __shared__ __align__(16) unsigned char smem[34944];
    _Float16* Xg  = (_Float16*)smem;                 // 8768 halfs = 17536 B
    _Float16* Zh4 = (_Float16*)(smem + 17536);       // 4*2112 halfs = 16896 B
    int* ind_s    = (int*)(smem + 34432);            // 128 ints
    float* red    = (float*)smem;                    // aliases dead Xg (512 f)

    const _Float16* hq = Hh + (size_t)q * 6144;
    f16x8 afr[4][3];
    #pragma unroll
    for (int ks = 0; ks < 4; ++ks)
        #pragma unroll
        for (int r = 0; r < 3; ++r)
            afr[ks][r] = *(const f16x8*)(hq + (r * 16 + n0) * 128 + ks * 32 + quad * 8);
    const float it = invtot[q];
    const int e0f = wv * 32 + quad * 8;
    f16x8 pf0 = *(const f16x8*)(W2th + (size_t)(0 * 16 + n0) * 2112 + e0f);
    f16x8 pf1 = *(const f16x8*)(W2th + (size_t)(1 * 16 + n0) * 2112 + e0f);
    if (tid < 128) {
        int kk = (tid < K_SEL) ? tid : tid - K_SEL;
        ind_s[tid] = indg[q * K_SEL + kk];
    }
    __syncthreads();

    int g_k[4], g_oct[4];
    #pragma unroll
    for (int i = 0; i < 4; ++i) {
        int t = tid + i * 256;
        g_k[i] = t >> 3;
        g_oct[i] = t & 7;
    }

    {   // pass-0 gather
        f16x8 v0[4];
        #pragma unroll
        for (int i = 0; i < 4; ++i)
            v0[i] = *(const f16x8*)(xlh + ((size_t)bt0 * 2048 + ind_s[g_k[i]]) * 64 + g_oct[i] * 8);
        #pragma unroll
        for (int i = 0; i < 4; ++i) {
            int base = g_oct[i] * 1096 + g_k[i];
            #pragma unroll
            for (int jj = 0; jj < 8; ++jj) Xg[base + 136 * jj] = v0[i][jj];
        }
    }
    __syncthreads();

    const int cA = wv * 16 + n0;
    const int cswz = cA * 136 + ((cA >> 3) << 3);

    #pragma unroll
    for (int p = 0; p < 4; ++p) {
        f16x8 vn[4];
        if (p < 3) {
            #pragma unroll
            for (int i = 0; i < 4; ++i)
                vn[i] = *(const f16x8*)(xlh + ((size_t)(bt0 + p + 1) * 2048 + ind_s[g_k[i]]) * 64 + g_oct[i] * 8);
        }
        f32x4 Dz[3];
        #pragma unroll
        for (int r = 0; r < 3; ++r) Dz[r] = (f32x4){0.f, 0.f, 0.f, 0.f};
        #pragma unroll
        for (int ks = 0; ks < 4; ++ks) {
            f16x8 bfr = *(const f16x8*)(&Xg[cswz + ks * 32 + quad * 8]);
            #pragma unroll
            for (int r = 0; r < 3; ++r)
                Dz[r] = __builtin_amdgcn_mfma_f32_16x16x32_f16(afr[ks][r], bfr, Dz[r], 0, 0, 0);
        }
        __syncthreads();          // Xg reads done
        #pragma unroll
        for (int r = 0; r < 3; ++r)
            #pragma unroll
            for (int reg = 0; reg < 4; ++reg) {
                int j = r * 16 + quad * 4 + reg;
                if (j < 33) Zh4[p * 2112 + j * 64 + cA] = (_Float16)Dz[r][reg];
            }
        if (p < 3) {
            #pragma unroll
            for (int i = 0; i < 4; ++i) {
                int base = g_oct[i] * 1096 + g_k[i];
                #pragma unroll
                for (int jj = 0; jj < 8; ++jj) Xg[base + 136 * jj] = vn[i][jj];
            }
            __syncthreads();
        }
    }
    __syncthreads();              // all Zh4 writes visible

    f32x4 D2[2][2];
    #pragma unroll
    for (int pp = 0; pp < 2; ++pp)
        #pragma unroll
        for (int dt = 0; dt < 2; ++dt) D2[pp][dt] = (f32x4){0.f, 0.f, 0.f, 0.f};
    {
        f16x8 a2 = {0, 0, 0, 0, 0, 0, 0, 0};
        if (n0 < 4) a2 = *(const f16x8*)(&Zh4[n0 * 2112 + e0f]);
        D2[0][0] = __builtin_amdgcn_mfma_f32_16x16x32_f16(a2, pf0, D2[0][0], 0, 0, 0);
        D2[0][1] = __builtin_amdgcn_mfma_f32_16x16x32_f16(a2, pf1, D2[0][1], 0, 0, 0);
    }
    int pp = 1;
    #pragma unroll 2
    for (int s = wv + 4; s < 66; s += 4) {
        const int e0 = s * 32 + quad * 8;
        f16x8 a2 = {0, 0, 0, 0, 0, 0, 0, 0};
        if (n0 < 4) a2 = *(const f16x8*)(&Zh4[n0 * 2112 + e0]);
        #pragma unroll
        for (int dt = 0; dt < 2; ++dt) {
            f16x8 bfr = *(const f16x8*)(W2th + (size_t)(dt * 16 + n0) * 2112 + e0);
            D2[pp][dt] = __builtin_amdgcn_mfma_f32_16x16x32_f16(a2, bfr, D2[pp][dt], 0, 0, 0);
        }
        pp ^= 1;
    }
    #pragma unroll
    for (int dt = 0; dt < 2; ++dt)
        D2[0][dt] = D2[0][dt] + D2[1][dt];

    if (quad == 0) {
        #pragma unroll
        for (int dt = 0; dt < 2; ++dt)
            #pragma unroll
            for (int reg = 0; reg < 4; ++reg)
                red[((wv * 2 + dt) * 4 + reg) * 16 + n0] = D2[0][dt][reg];
    }
    __syncthreads();
    if (tid < 128) {
        const int bt = tid >> 5;
        const int d = tid & 31;
        const int dt = d >> 4;
        const int dn = d & 15;
        float s = 0.0f;
        #pragma unroll
        for (int w2 = 0; w2 < 4; ++w2)
            s += red[((w2 * 2 + dt) * 4 + bt) * 16 + dn];
        out[((size_t)(bt0 + bt) * 512 + q) * 32 + d] = bias[d] + it * s;
    }
}

// ---------------------------------------------------------------------------
extern "C" void kernel_launch(void* const* d_in, const int* in_sizes, int n_in,
                              void* d_out, int out_size, void* d_ws, size_t ws_size,
                              hipStream_t stream) {
    const float* x     = (const float*)d_in[0];   // (2,4,2048,64)
    const float* pos   = (const float*)d_in[1];   // (2048,2)
    const float* qpos  = (const float*)d_in[2];   // (512,2)
    const float* W_lin = (const float*)d_in[3];   // (64,64)
    const float* b_lin = (const float*)d_in[4];   // (64)
    const float* Bmat  = (const float*)d_in[5];   // (2,16)
    const float* W1    = (const float*)d_in[6];   // (32,32)
    const float* b1    = (const float*)d_in[7];   // (32)
    const float* W2    = (const float*)d_in[8];   // (2048,32)
    const float* filt  = (const float*)d_in[9];   // (2048)
    const float* bias  = (const float*)d_in[10];  // (32)
    float* out = (float*)d_out;

    float* ws = (float*)d_ws;
    _Float16* xlh    = (_Float16*)ws;               // 1048576 halfs
    _Float16* Hh     = (_Float16*)(ws + 524288);    // 512*6144 halfs
    int*      indg   = (int*)(ws + 2097152);        // 52736 ints
    _Float16* W2th   = (_Float16*)(ws + 2150144);   // 32*2112 halfs
    float*    invtot = ws + 2183936;                // 512 floats

    k12<<<768, 512, 0, stream>>>(pos, qpos, Bmat, W1, b1, Hh, indg, invtot,
                                 x, W_lin, b_lin, xlh, W2, filt, W2th);
    k3_main<<<1024, 256, 0, stream>>>(xlh, Hh, indg, W2th, bias, invtot, out);
}